// Round 9
// baseline (1295.202 us; speedup 1.0000x reference)
//
#include <hip/hip_runtime.h>
#include <hip/hip_bf16.h>

#define N_NODES 50000
#define N_EDGES 800000
#define IN_FEAT 256
#define UNITS   128
#define GRID_SZ 1024                 // 4 blocks/CU x 256 CUs: all resident
#define GEMM_B  782                  // ceil(50000/64) gemm tiles
#define RANK_B  (GRID_SZ - GEMM_B)   // 242 blocks for edge_rank

typedef unsigned short ushort_t;
typedef __bf16 bf16x8 __attribute__((ext_vector_type(8)));
typedef float  f32x4  __attribute__((ext_vector_type(4)));
typedef unsigned short ushort8 __attribute__((ext_vector_type(8)));

__device__ __forceinline__ ushort_t f2bf(float f) {
    unsigned u = __float_as_uint(f);
    u += 0x7fff + ((u >> 16) & 1);      // round-to-nearest-even
    return (ushort_t)(u >> 16);
}

__device__ __forceinline__ float edge_score(float at, float as) {
    float s = at + as;
    s = s > 0.f ? s : 0.2f * s;          // leaky_relu
    s = fminf(fmaxf(s, -2.f), 2.f);      // clip
    return __expf(s);
}

// Device-scope grid barrier: one fresh counter per phase (memset-zeroed each
// call). Release fence writes back XCD L2; acquire side invalidates, so
// cross-XCD reads after the barrier see all pre-barrier writes (G16).
__device__ __forceinline__ void grid_barrier(int* cnt) {
    __syncthreads();                     // all waves' stores drained to L2
    if (threadIdx.x == 0) {
        __threadfence();                 // agent release: L2 writeback
        __hip_atomic_fetch_add(cnt, 1, __ATOMIC_ACQ_REL, __HIP_MEMORY_SCOPE_AGENT);
        while (__hip_atomic_load(cnt, __ATOMIC_ACQUIRE, __HIP_MEMORY_SCOPE_AGENT)
               < GRID_SZ)
            __builtin_amdgcn_s_sleep(8);
        __threadfence();                 // agent acquire: invalidate stale lines
    }
    __syncthreads();
}

// ---------------------------------------------------------------------------
// Persistent 5-phase kernel. Phase bodies are the R5-proven code verbatim;
// only the block->work mapping changed (stride loops / block partitions).
// ---------------------------------------------------------------------------
__global__ __launch_bounds__(256, 4) void mega(
    const float* __restrict__ A, const int* __restrict__ edges,
    const float* __restrict__ W, const float* __restrict__ ka,
    ushort_t* __restrict__ wt, ushort_t* __restrict__ hb,
    float* __restrict__ a_tgt, float* __restrict__ a_src,
    int* __restrict__ counts, int* __restrict__ node_off,
    int* __restrict__ rank_, int2* __restrict__ csr,
    int* __restrict__ bar, float* __restrict__ out)
{
    __shared__ __align__(16) ushort_t As[64 * 40];    // 5 KB
    __shared__ __align__(16) ushort_t Bs[128 * 40];   // 10 KB
    __shared__ int wsum[4];
    __shared__ int total_sh;

    const int tid = threadIdx.x;
    const int bid = blockIdx.x;
    const int M = N_NODES, E = N_EDGES;

    // ================= P0: Wt transpose+cvt, zero counts ==================
    {
        int i = bid * 256 + tid;                       // 0..262143, one pass
        if (i < UNITS * IN_FEAT) {
            int n = i >> 8;
            int k = i & 255;
            wt[i] = f2bf(W[(size_t)k * UNITS + n]);
        }
        if (i < M) counts[i] = 0;
    }
    grid_barrier(&bar[0]);

    // ================= P1: gemm (blocks 0..781) || edge_rank (rest) =======
    if (bid < GEMM_B) {
        const int lane = tid & 63;
        const int wv   = tid >> 6;
        const int wy   = wv >> 1;
        const int wx   = wv & 1;
        const int row0 = bid * 64;
        const int quad = lane >> 4;
        const int cl   = lane & 15;

        f32x4 acc[2][4] = {};

        const int ar = tid >> 2, aq = tid & 3;
        const int gr = min(row0 + ar, M - 1);
        const float*    aptr   = A + (size_t)gr * IN_FEAT + aq * 8;
        ushort_t*       as_dst = As + ar * 40 + aq * 8;
        const int br = tid >> 1, bh = tid & 1;
        const ushort_t* wptr   = wt + br * IN_FEAT + bh * 16;
        ushort_t*       bs_dst = Bs + br * 40 + bh * 16;

        for (int kc = 0; kc < IN_FEAT; kc += 32) {
            float4 f0 = *(const float4*)(aptr + kc);
            float4 f1 = *(const float4*)(aptr + kc + 4);
            ushort8 w0 = *(const ushort8*)(wptr + kc);
            ushort8 w1 = *(const ushort8*)(wptr + kc + 8);
            ushort8 u;
            u[0] = f2bf(f0.x); u[1] = f2bf(f0.y); u[2] = f2bf(f0.z); u[3] = f2bf(f0.w);
            u[4] = f2bf(f1.x); u[5] = f2bf(f1.y); u[6] = f2bf(f1.z); u[7] = f2bf(f1.w);
            __syncthreads();
            *(ushort8*)as_dst = u;
            *(ushort8*)bs_dst        = w0;
            *(ushort8*)(bs_dst + 8)  = w1;
            __syncthreads();

            bf16x8 af[2], bff[4];
#pragma unroll
            for (int mi = 0; mi < 2; ++mi)
                af[mi] = *(const bf16x8*)(As + (wy * 32 + mi * 16 + cl) * 40 + quad * 8);
#pragma unroll
            for (int ni = 0; ni < 4; ++ni)
                bff[ni] = *(const bf16x8*)(Bs + (wx * 64 + ni * 16 + cl) * 40 + quad * 8);
#pragma unroll
            for (int mi = 0; mi < 2; ++mi)
#pragma unroll
                for (int ni = 0; ni < 4; ++ni)
                    acc[mi][ni] = __builtin_amdgcn_mfma_f32_16x16x32_bf16(
                        af[mi], bff[ni], acc[mi][ni], 0, 0, 0);
        }

#pragma unroll
        for (int mi = 0; mi < 2; ++mi) {
#pragma unroll
            for (int ni = 0; ni < 4; ++ni) {
                int col = wx * 64 + ni * 16 + cl;
#pragma unroll
                for (int r = 0; r < 4; ++r) {
                    int row = row0 + wy * 32 + mi * 16 + quad * 4 + r;
                    if (row < M)
                        hb[(size_t)row * UNITS + col] = f2bf(acc[mi][ni][r]);
                }
            }
        }
    } else {
        for (int e = (bid - GEMM_B) * 256 + tid; e < E; e += RANK_B * 256) {
            int2 ts = ((const int2*)edges)[e];   // (tgt, src)
            rank_[e] = atomicAdd(&counts[ts.x], 1);
        }
    }
    grid_barrier(&bar[1]);

    // ================= P2: scan (block 0) || attn_dots (blocks 1..) =======
    if (bid == 0) {
        // R6/R8-proven single-block chunked scan; reads counts (padded to
        // 57600 ints in ws, OOB values masked below).
        const int lane = tid & 63, wvq = tid >> 6;
        const int CH = 256 * 32;
        const int nch = (M + CH - 1) / CH;
        int base = 0;
        for (int ch = 0; ch < nch; ++ch) {
            int i0 = ch * CH + tid * 32;
            int a[32];
#pragma unroll
            for (int j = 0; j < 8; ++j) {
                int4 v = *(const int4*)(counts + i0 + j * 4);
                a[j * 4 + 0] = v.x; a[j * 4 + 1] = v.y;
                a[j * 4 + 2] = v.z; a[j * 4 + 3] = v.w;
            }
            int run = 0;
#pragma unroll
            for (int k = 0; k < 32; ++k) {
                int val = (i0 + k < M) ? a[k] : 0;
                a[k] = run;
                run += val;
            }
            int incl = run;
#pragma unroll
            for (int off = 1; off < 64; off <<= 1) {
                int t = __shfl_up(incl, off);
                if (lane >= off) incl += t;
            }
            if (lane == 63) wsum[wvq] = incl;
            __syncthreads();
            if (tid == 0) {
                int r = 0;
#pragma unroll
                for (int i = 0; i < 4; ++i) { int x = wsum[i]; wsum[i] = r; r += x; }
                total_sh = r;
            }
            __syncthreads();
            int tb = base + wsum[wvq] + (incl - run);
#pragma unroll
            for (int k = 0; k < 32; ++k)
                if (i0 + k < M) node_off[i0 + k] = tb + a[k];
            base += total_sh;
            __syncthreads();
        }
        if (tid == 0) node_off[M] = base;
    } else {
        int lane = tid & 63;
        for (int n = (bid - 1) * 4 + (tid >> 6); n < M; n += (GRID_SZ - 1) * 4) {
            unsigned u = *(const unsigned*)(hb + (size_t)n * UNITS + lane * 2);
            float h0 = __uint_as_float(u << 16);
            float h1 = __uint_as_float(u & 0xffff0000u);
            float2 kt = *(const float2*)(ka + lane * 2);
            float2 ks = *(const float2*)(ka + UNITS + lane * 2);
            float pt = h0 * kt.x + h1 * kt.y;
            float ps = h0 * ks.x + h1 * ks.y;
#pragma unroll
            for (int off = 32; off > 0; off >>= 1) {
                pt += __shfl_down(pt, off);
                ps += __shfl_down(ps, off);
            }
            if (lane == 0) { a_tgt[n] = pt; a_src[n] = ps; }
        }
    }
    grid_barrier(&bar[2]);

    // ================= P3: build_csr (all blocks, stride) =================
    for (int e = bid * 256 + tid; e < E; e += GRID_SZ * 256) {
        int2 ts = ((const int2*)edges)[e];
        float sc = edge_score(a_tgt[ts.x], a_src[ts.y]);
        int pos = node_off[ts.x] + rank_[e];
        csr[pos] = make_int2(ts.y, __float_as_int(sc));
    }
    grid_barrier(&bar[3]);

    // ================= P4: aggregate (wave per node, stride) ==============
    {
        const int lane = tid & 63;
        const int g = lane >> 4;
        const int c = lane & 15;
        for (int wid = bid * 4 + (tid >> 6); wid < M; wid += GRID_SZ * 4) {
            int beg = node_off[wid];
            int end = node_off[wid + 1];

            float acc[8] = {};
            float wacc = 0.f;

            for (int base = beg; base < end; base += 64) {
                int cd = min(64, end - base);
                int   s_v = 0;
                float w_v = 0.f;
                if (lane < cd) {
                    int2 sw = csr[base + lane];
                    s_v = sw.x;
                    w_v = __int_as_float(sw.y);
                }
                wacc += w_v;
                int nstep = (cd + 3) >> 2;
#pragma unroll 4
                for (int t = 0; t < nstep; ++t) {
                    int slot = t * 4 + g;
                    int   src = __shfl(s_v, slot);
                    float w   = __shfl(w_v, slot);
                    uint4 u = *(const uint4*)(hb + (size_t)src * UNITS + c * 8);
                    acc[0] += w * __uint_as_float(u.x << 16);
                    acc[1] += w * __uint_as_float(u.x & 0xffff0000u);
                    acc[2] += w * __uint_as_float(u.y << 16);
                    acc[3] += w * __uint_as_float(u.y & 0xffff0000u);
                    acc[4] += w * __uint_as_float(u.z << 16);
                    acc[5] += w * __uint_as_float(u.z & 0xffff0000u);
                    acc[6] += w * __uint_as_float(u.w << 16);
                    acc[7] += w * __uint_as_float(u.w & 0xffff0000u);
                }
            }

#pragma unroll
            for (int i = 0; i < 8; ++i) {
                acc[i] += __shfl_xor(acc[i], 16);
                acc[i] += __shfl_xor(acc[i], 32);
            }
#pragma unroll
            for (int off = 32; off > 0; off >>= 1) wacc += __shfl_xor(wacc, off);
            float scale = (end > beg) ? 1.0f / wacc : 0.0f;

            if (g == 0) {
                float4 o0 = make_float4(acc[0] * scale, acc[1] * scale,
                                        acc[2] * scale, acc[3] * scale);
                float4 o1 = make_float4(acc[4] * scale, acc[5] * scale,
                                        acc[6] * scale, acc[7] * scale);
                float* dst = out + (size_t)wid * UNITS + c * 8;
                *(float4*)dst       = o0;
                *(float4*)(dst + 4) = o1;
            }
        }
    }
}

// ---------------------------------------------------------------------------
extern "C" void kernel_launch(void* const* d_in, const int* in_sizes, int n_in,
                              void* d_out, int out_size, void* d_ws, size_t ws_size,
                              hipStream_t stream) {
    const float* node_states = (const float*)d_in[0];
    const int*   edges       = (const int*)d_in[1];   // int32 pairs (tgt,src)
    const float* W           = (const float*)d_in[2];
    const float* ka          = (const float*)d_in[3];
    float*       out         = (float*)d_out;

    // workspace layout (all 16B-aligned; NO aliasing between wt and csr —
    // single-kernel L1 reuse would see stale lines; no trailing backslashes!)
    int*      bar     = (int*)d_ws;                        // 64 ints (zeroed)
    ushort_t* hb      = (ushort_t*)(bar + 64);             // 6,400,000 bf16
    float*    a_tgt   = (float*)(hb + (size_t)N_NODES * UNITS); // 50,000
    float*    a_src   = a_tgt + N_NODES;                   // 50,000
    int*      counts  = (int*)(a_src + N_NODES);           // 57,600 (scan OOB pad)
    int*      node_off= counts + 57600;                    // 50,004
    int*      rank_   = node_off + 50004;                  // 800,000
    int2*     csr     = (int2*)(rank_ + N_EDGES);          // 800,000 int2
    ushort_t* wt      = (ushort_t*)(csr + N_EDGES);        // 32,768 bf16
    // total ~23 MB of the 268 MB ws

    (void)hipMemsetAsync(bar, 0, 64 * sizeof(int), stream);
    mega<<<GRID_SZ, 256, 0, stream>>>(node_states, edges, W, ka, wt, hb,
                                      a_tgt, a_src, counts, node_off,
                                      rank_, csr, bar, out);
}

// Round 10
// 222.491 us; speedup vs baseline: 5.8214x; 5.8214x over previous
//
#include <hip/hip_runtime.h>
#include <hip/hip_bf16.h>

#define N_NODES 50000
#define N_EDGES 800000
#define IN_FEAT 256
#define UNITS   128

#define GEMM_B   782                  // ceil(50000/64) gemm tiles
#define RANK_B   3125                 // ceil(800000/256) rank chunks
#define TOT_B    (GEMM_B + RANK_B)    // 3907; gemm on bid%5==0 (0..3905)

typedef unsigned short ushort_t;
typedef __bf16 bf16x8 __attribute__((ext_vector_type(8)));
typedef float  f32x4  __attribute__((ext_vector_type(4)));
typedef unsigned short ushort8 __attribute__((ext_vector_type(8)));

__device__ __forceinline__ ushort_t f2bf(float f) {
    unsigned u = __float_as_uint(f);
    u += 0x7fff + ((u >> 16) & 1);      // round-to-nearest-even
    return (ushort_t)(u >> 16);
}

__device__ __forceinline__ float edge_score(float at, float as) {
    float s = at + as;
    s = s > 0.f ? s : 0.2f * s;          // leaky_relu
    s = fminf(fmaxf(s, -2.f), 2.f);      // clip
    return __expf(s);
}

// ---------------------------------------------------------------------------
// K0: Wt[n][k] = bf16(W[k][n])  (R5-proven)
// ---------------------------------------------------------------------------
__global__ __launch_bounds__(256) void prep_wt(const float* __restrict__ W,
                                               ushort_t* __restrict__ Wt) {
    int i = blockIdx.x * 256 + threadIdx.x;
    if (i >= UNITS * IN_FEAT) return;
    int n = i >> 8;
    int k = i & 255;
    Wt[i] = f2bf(W[(size_t)k * UNITS + n]);
}

// ---------------------------------------------------------------------------
// K1 (fused, interleaved): bid%5==0 -> gemm tile bid/5 (R5-proven body),
// else -> edge_rank chunk (R5-proven body). Interleaving puts both phases in
// the initially-resident block set so MFMA waves hide atomic latency (m114).
// ---------------------------------------------------------------------------
__global__ __launch_bounds__(256) void fusedGR(const float* __restrict__ A,
                                               const ushort_t* __restrict__ Wt,
                                               ushort_t* __restrict__ Hb, int M,
                                               const int* __restrict__ edges,
                                               int* __restrict__ counts,
                                               int* __restrict__ rank_, int E) {
    const int bid = blockIdx.x;
    const int tid = threadIdx.x;

    if (bid % 5 != 0) {
        // ---- edge_rank: one 256-edge chunk ----
        int rankIdx = bid - bid / 5 - 1;          // 0..3124
        int e = rankIdx * 256 + tid;
        if (e < E) {
            int2 ts = ((const int2*)edges)[e];    // (tgt, src)
            rank_[e] = atomicAdd(&counts[ts.x], 1);
        }
        return;
    }

    // ---- gemm: tile bid/5 (R5 body verbatim) ----
    __shared__ __align__(16) ushort_t As[64 * 40];    // 5 KB
    __shared__ __align__(16) ushort_t Bs[128 * 40];   // 10 KB
    const int lane = tid & 63;
    const int wv   = tid >> 6;
    const int wy   = wv >> 1;
    const int wx   = wv & 1;
    const int row0 = (bid / 5) * 64;
    const int quad = lane >> 4;
    const int cl   = lane & 15;

    f32x4 acc[2][4] = {};

    const int ar = tid >> 2, aq = tid & 3;
    const int gr = min(row0 + ar, M - 1);
    const float*    aptr   = A + (size_t)gr * IN_FEAT + aq * 8;
    ushort_t*       as_dst = As + ar * 40 + aq * 8;
    const int br = tid >> 1, bh = tid & 1;
    const ushort_t* wptr   = Wt + br * IN_FEAT + bh * 16;
    ushort_t*       bs_dst = Bs + br * 40 + bh * 16;

    for (int kc = 0; kc < IN_FEAT; kc += 32) {
        float4 f0 = *(const float4*)(aptr + kc);
        float4 f1 = *(const float4*)(aptr + kc + 4);
        ushort8 w0 = *(const ushort8*)(wptr + kc);
        ushort8 w1 = *(const ushort8*)(wptr + kc + 8);
        ushort8 u;
        u[0] = f2bf(f0.x); u[1] = f2bf(f0.y); u[2] = f2bf(f0.z); u[3] = f2bf(f0.w);
        u[4] = f2bf(f1.x); u[5] = f2bf(f1.y); u[6] = f2bf(f1.z); u[7] = f2bf(f1.w);
        __syncthreads();
        *(ushort8*)as_dst = u;
        *(ushort8*)bs_dst        = w0;
        *(ushort8*)(bs_dst + 8)  = w1;
        __syncthreads();

        bf16x8 af[2], bff[4];
#pragma unroll
        for (int mi = 0; mi < 2; ++mi)
            af[mi] = *(const bf16x8*)(As + (wy * 32 + mi * 16 + cl) * 40 + quad * 8);
#pragma unroll
        for (int ni = 0; ni < 4; ++ni)
            bff[ni] = *(const bf16x8*)(Bs + (wx * 64 + ni * 16 + cl) * 40 + quad * 8);
#pragma unroll
        for (int mi = 0; mi < 2; ++mi)
#pragma unroll
            for (int ni = 0; ni < 4; ++ni)
                acc[mi][ni] = __builtin_amdgcn_mfma_f32_16x16x32_bf16(
                    af[mi], bff[ni], acc[mi][ni], 0, 0, 0);
    }

#pragma unroll
    for (int mi = 0; mi < 2; ++mi) {
#pragma unroll
        for (int ni = 0; ni < 4; ++ni) {
            int col = wx * 64 + ni * 16 + cl;
#pragma unroll
            for (int r = 0; r < 4; ++r) {
                int row = row0 + wy * 32 + mi * 16 + quad * 4 + r;
                if (row < M)
                    Hb[(size_t)row * UNITS + col] = f2bf(acc[mi][ni][r]);
            }
        }
    }
}

// ---------------------------------------------------------------------------
// K2 (fused, R6-proven): block 0 -> single-block chunked scan of counts ->
// node_off; blocks 1.. -> attn_dots (one wave per node).
// ---------------------------------------------------------------------------
__global__ __launch_bounds__(256) void fusedB(const ushort_t* __restrict__ Hb,
                                              const float* __restrict__ ka,
                                              float* __restrict__ a_tgt,
                                              float* __restrict__ a_src,
                                              const int* __restrict__ counts,
                                              int* __restrict__ node_off, int M) {
    const int tid = threadIdx.x;

    if (blockIdx.x == 0) {
        __shared__ int wsum[4];
        __shared__ int total_sh;
        const int lane = tid & 63, wv = tid >> 6;
        const int CH = 256 * 32;
        const int nch = (M + CH - 1) / CH;     // 7
        int base = 0;
        for (int ch = 0; ch < nch; ++ch) {
            int i0 = ch * CH + tid * 32;
            int a[32];
#pragma unroll
            for (int j = 0; j < 8; ++j) {
                int4 v = *(const int4*)(counts + i0 + j * 4);  // pad-safe OOB
                a[j * 4 + 0] = v.x; a[j * 4 + 1] = v.y;
                a[j * 4 + 2] = v.z; a[j * 4 + 3] = v.w;
            }
            int run = 0;
#pragma unroll
            for (int k = 0; k < 32; ++k) {
                int val = (i0 + k < M) ? a[k] : 0;
                a[k] = run;
                run += val;
            }
            int incl = run;
#pragma unroll
            for (int off = 1; off < 64; off <<= 1) {
                int t = __shfl_up(incl, off);
                if (lane >= off) incl += t;
            }
            if (lane == 63) wsum[wv] = incl;
            __syncthreads();
            if (tid == 0) {
                int r = 0;
#pragma unroll
                for (int i = 0; i < 4; ++i) { int x = wsum[i]; wsum[i] = r; r += x; }
                total_sh = r;
            }
            __syncthreads();
            int tb = base + wsum[wv] + (incl - run);
#pragma unroll
            for (int k = 0; k < 32; ++k)
                if (i0 + k < M) node_off[i0 + k] = tb + a[k];
            base += total_sh;
            __syncthreads();
        }
        if (tid == 0) node_off[M] = base;
        return;
    }

    int wid  = (blockIdx.x - 1) * 4 + (tid >> 6);
    int lane = tid & 63;
    if (wid >= M) return;
    unsigned u = *(const unsigned*)(Hb + (size_t)wid * UNITS + lane * 2);
    float h0 = __uint_as_float(u << 16);
    float h1 = __uint_as_float(u & 0xffff0000u);
    float2 kt = *(const float2*)(ka + lane * 2);
    float2 ks = *(const float2*)(ka + UNITS + lane * 2);
    float pt = h0 * kt.x + h1 * kt.y;
    float ps = h0 * ks.x + h1 * ks.y;
#pragma unroll
    for (int off = 32; off > 0; off >>= 1) {
        pt += __shfl_down(pt, off);
        ps += __shfl_down(ps, off);
    }
    if (lane == 0) { a_tgt[wid] = pt; a_src[wid] = ps; }
}

// ---------------------------------------------------------------------------
// K4: atomic-free CSR scatter (R5-proven, unmodified).
// ---------------------------------------------------------------------------
__global__ __launch_bounds__(256) void build_csr(const int* __restrict__ edges,
                                                 const int* __restrict__ rank_,
                                                 const float* __restrict__ at,
                                                 const float* __restrict__ as,
                                                 const int* __restrict__ node_off,
                                                 int2* __restrict__ csr, int E) {
    int e = blockIdx.x * 256 + threadIdx.x;
    if (e >= E) return;
    int2 ts = ((const int2*)edges)[e];
    float sc = edge_score(at[ts.x], as[ts.y]);
    int pos = node_off[ts.x] + rank_[e];
    csr[pos] = make_int2(ts.y, __float_as_int(sc));
}

// ---------------------------------------------------------------------------
// K5: one wave per target node; 4 edge-slots x 16 feature-lanes (R5-proven).
// ---------------------------------------------------------------------------
__global__ __launch_bounds__(256) void aggregate(const ushort_t* __restrict__ Hb,
                                                 const int* __restrict__ node_off,
                                                 const int2* __restrict__ csr,
                                                 float* __restrict__ out, int M) {
    int wid  = (int)((blockIdx.x * 256 + threadIdx.x) >> 6);
    int lane = threadIdx.x & 63;
    if (wid >= M) return;
    const int g = lane >> 4;
    const int c = lane & 15;
    int beg = node_off[wid];
    int end = node_off[wid + 1];

    float acc[8] = {};
    float wacc = 0.f;

    for (int base = beg; base < end; base += 64) {
        int cd = min(64, end - base);
        int   s_v = 0;
        float w_v = 0.f;
        if (lane < cd) {
            int2 sw = csr[base + lane];
            s_v = sw.x;
            w_v = __int_as_float(sw.y);
        }
        wacc += w_v;
        int nstep = (cd + 3) >> 2;
#pragma unroll 4
        for (int t = 0; t < nstep; ++t) {
            int slot = t * 4 + g;
            int   src = __shfl(s_v, slot);
            float w   = __shfl(w_v, slot);
            uint4 u = *(const uint4*)(Hb + (size_t)src * UNITS + c * 8);
            acc[0] += w * __uint_as_float(u.x << 16);
            acc[1] += w * __uint_as_float(u.x & 0xffff0000u);
            acc[2] += w * __uint_as_float(u.y << 16);
            acc[3] += w * __uint_as_float(u.y & 0xffff0000u);
            acc[4] += w * __uint_as_float(u.z << 16);
            acc[5] += w * __uint_as_float(u.z & 0xffff0000u);
            acc[6] += w * __uint_as_float(u.w << 16);
            acc[7] += w * __uint_as_float(u.w & 0xffff0000u);
        }
    }

#pragma unroll
    for (int i = 0; i < 8; ++i) {
        acc[i] += __shfl_xor(acc[i], 16);
        acc[i] += __shfl_xor(acc[i], 32);
    }
#pragma unroll
    for (int off = 32; off > 0; off >>= 1) wacc += __shfl_xor(wacc, off);
    float scale = (end > beg) ? 1.0f / wacc : 0.0f;

    if (g == 0) {
        float4 o0 = make_float4(acc[0] * scale, acc[1] * scale,
                                acc[2] * scale, acc[3] * scale);
        float4 o1 = make_float4(acc[4] * scale, acc[5] * scale,
                                acc[6] * scale, acc[7] * scale);
        float* dst = out + (size_t)wid * UNITS + c * 8;
        *(float4*)dst       = o0;
        *(float4*)(dst + 4) = o1;
    }
}

// ---------------------------------------------------------------------------
extern "C" void kernel_launch(void* const* d_in, const int* in_sizes, int n_in,
                              void* d_out, int out_size, void* d_ws, size_t ws_size,
                              hipStream_t stream) {
    const float* node_states = (const float*)d_in[0];
    const int*   edges       = (const int*)d_in[1];   // int32 pairs (tgt,src)
    const float* W           = (const float*)d_in[2];
    const float* ka          = (const float*)d_in[3];
    float*       out         = (float*)d_out;

    const int M = N_NODES, E = N_EDGES;

    // workspace layout (no trailing backslashes in comments!)
    ushort_t* hb      = (ushort_t*)d_ws;                  // M*128 bf16 = 12.8 MB
    float*    a_tgt   = (float*)(hb + (size_t)M * UNITS); // M
    float*    a_src   = a_tgt + M;                        // M
    int*      counts  = (int*)(a_src + M);                // 57,600 (scan OOB pad)
    int*      node_off= counts + 57600;                   // M+4
    int*      rank_   = node_off + M + 4;                 // E
    int2*     csr     = (int2*)(rank_ + E);               // E int2
    // Wt (64KB bf16) aliases csr (R3-R5-proven): only prep_wt/fusedGR touch
    // wt, both complete before build_csr writes csr. Stream-ordered => safe.
    ushort_t* wt      = (ushort_t*)csr;

    (void)hipMemsetAsync(counts, 0, (size_t)M * sizeof(int), stream);

    prep_wt   <<<(UNITS * IN_FEAT + 255) / 256, 256, 0, stream>>>(W, wt);
    fusedGR   <<<TOT_B, 256, 0, stream>>>(node_states, wt, hb, M,
                                          edges, counts, rank_, E);
    fusedB    <<<1 + (M + 3) / 4, 256, 0, stream>>>(hb, ka, a_tgt, a_src,
                                                    counts, node_off, M);
    build_csr <<<(E + 255) / 256, 256, 0, stream>>>(edges, rank_, a_tgt, a_src,
                                                    node_off, csr, E);
    aggregate <<<(M * 64 + 255) / 256, 256, 0, stream>>>(hb, node_off, csr, out, M);
}